// Round 14
// baseline (273.642 us; speedup 1.0000x reference)
//
#include <hip/hip_runtime.h>
#include <hip/hip_bf16.h>
#include <stdint.h>

#define B_ 4
#define S_ 2048
#define H_ 1024
#define NH_ 16
#define HD_ 64

typedef __attribute__((ext_vector_type(8))) short short8;
typedef __attribute__((ext_vector_type(4))) float f32x4;
typedef __attribute__((ext_vector_type(16))) float f32x16;
typedef __attribute__((ext_vector_type(4))) unsigned short ushort4v;
typedef __attribute__((ext_vector_type(2))) unsigned uint2v;

__device__ __forceinline__ unsigned short f2bf(float f) {
  union { float f; unsigned u; } x; x.f = f;
  unsigned r = x.u + 0x7fffu + ((x.u >> 16) & 1u);
  return (unsigned short)(r >> 16);
}

__device__ __forceinline__ unsigned cvtpk_bf16(float a, float b) {
  unsigned r;
  asm("v_cvt_pk_bf16_f32 %0, %1, %2" : "=v"(r) : "v"(a), "v"(b));
  return r;
}

#define ALDS16(g, l) \
  __builtin_amdgcn_global_load_lds((const __attribute__((address_space(1))) void*)(g), \
                                   (__attribute__((address_space(3))) void*)(l), 16, 0, 0)

// ---------------- input fp32 -> bf16 convert ----------------
__global__ __launch_bounds__(256) void cvt_in(
    const float* __restrict__ q, const float* __restrict__ k, const float* __restrict__ v,
    unsigned short* __restrict__ oq, unsigned short* __restrict__ ok2, unsigned short* __restrict__ ov) {
  const int z = blockIdx.z;
  const float* src = z == 0 ? q : (z == 1 ? k : v);
  unsigned short* dst = z == 0 ? oq : (z == 1 ? ok2 : ov);
  const size_t i = ((size_t)blockIdx.x * 256 + threadIdx.x) * 8;
  const f32x4 a = *reinterpret_cast<const f32x4*>(src + i);
  const f32x4 c = *reinterpret_cast<const f32x4*>(src + i + 4);
  short8 o;
#pragma unroll
  for (int j = 0; j < 4; ++j) { o[j] = (short)f2bf(a[j]); o[j + 4] = (short)f2bf(c[j]); }
  *reinterpret_cast<short8*>(dst + i) = o;
}

// ---------------- mask fp32 -> bit pack (bit set = KEEP, i.e. mask==0) ----------------
__global__ __launch_bounds__(256) void packmask(
    const float* __restrict__ mask, unsigned long long* __restrict__ mb) {
  const int w = threadIdx.x >> 6, lane = threadIdx.x & 63;
  const int wbase = (blockIdx.x * 4 + w) * 32;
#pragma unroll 8
  for (int i = 0; i < 32; ++i) {
    const float v = mask[(size_t)(wbase + i) * 64 + lane];
    const unsigned long long bits = __ballot(v == 0.0f);
    if (lane == 0) mb[wbase + i] = bits;
  }
}

// ---------------- weight fp32 -> bf16 transpose (Wt[n][k] = W[k][n]) ----------------
__global__ __launch_bounds__(256) void cvt_w(
    const float* __restrict__ Wq, const float* __restrict__ Wk,
    const float* __restrict__ Wv, const float* __restrict__ Wo,
    unsigned short* __restrict__ wt) {
  __shared__ float tile[64][65];
  const int z = blockIdx.z;
  const float* W = z == 0 ? Wq : (z == 1 ? Wk : (z == 2 ? Wv : Wo));
  unsigned short* out = wt + (size_t)z * H_ * H_;
  const int t = threadIdx.x;
  const int r0 = blockIdx.y * 64, c0 = blockIdx.x * 64;
  const int tr = t >> 4, tc = (t & 15) * 4;
#pragma unroll
  for (int rr = 0; rr < 4; ++rr) {
    const int row = rr * 16 + tr;
    const f32x4 val = *reinterpret_cast<const f32x4*>(W + (size_t)(r0 + row) * H_ + c0 + tc);
#pragma unroll
    for (int j = 0; j < 4; ++j) tile[row][tc + j] = val[j];
  }
  __syncthreads();
#pragma unroll
  for (int rr = 0; rr < 4; ++rr) {
    const int c = rr * 16 + tr;
    ushort4v o;
#pragma unroll
    for (int j = 0; j < 4; ++j) o[j] = f2bf(tile[tc + j][c]);
    *reinterpret_cast<ushort4v*>(out + (size_t)(c0 + c) * H_ + r0 + tc) = o;
  }
}

// ---------------- GEMM body: C = (X @ Wt^T + bias) * oscale ----------------
// OUTMODE 0: bf16 head-split [B,NH,S,HD]. 1: fp32 flat [M,H]. 2: bf16 V-transposed.
template <int OUTMODE>
__device__ __forceinline__ void gemm_body(
    const unsigned short* __restrict__ X, const unsigned short* __restrict__ Wt,
    const float* __restrict__ bias, float oscale, unsigned short* __restrict__ obf,
    float* __restrict__ of32) {
  __shared__ unsigned short As[128 * 64];
  __shared__ unsigned short Bs[128 * 64];
  const int t = threadIdx.x;
  const int w = t >> 6, l = t & 63;
  const int lr = l & 15, lg = l >> 4;
  const int brow = blockIdx.x * 128, bcol = blockIdx.y * 128;
  const int wr = (w >> 1) * 64, wc = (w & 1) * 64;
  f32x4 acc[4][4] = {};
  const unsigned short* xb = X + (size_t)brow * 1024;
  const unsigned short* wb = Wt + (size_t)bcol * 1024;
  int srow[4], skl[4];
#pragma unroll
  for (int j = 0; j < 4; ++j) {
    const int c = t + j * 256;
    srow[j] = c >> 3;
    skl[j] = ((c & 7) ^ ((c >> 3) & 7)) * 8;
  }
  for (int kt = 0; kt < 1024; kt += 64) {
#pragma unroll
    for (int j = 0; j < 4; ++j) {
      ALDS16(xb + (size_t)srow[j] * 1024 + kt + skl[j], As + (t + j * 256) * 8);
      ALDS16(wb + (size_t)srow[j] * 1024 + kt + skl[j], Bs + (t + j * 256) * 8);
    }
    __syncthreads();
#pragma unroll
    for (int kk = 0; kk < 2; ++kk) {
      short8 af[4], bf[4];
#pragma unroll
      for (int m = 0; m < 4; ++m) {
        const int ra = wr + m * 16 + lr;
        af[m] = *reinterpret_cast<const short8*>(As + ra * 64 + ((kk * 4 + lg) ^ (ra & 7)) * 8);
      }
#pragma unroll
      for (int n = 0; n < 4; ++n) {
        const int rb = wc + n * 16 + lr;
        bf[n] = *reinterpret_cast<const short8*>(Bs + rb * 64 + ((kk * 4 + lg) ^ (rb & 7)) * 8);
      }
#pragma unroll
      for (int m = 0; m < 4; ++m)
#pragma unroll
        for (int n = 0; n < 4; ++n)
          acc[m][n] = __builtin_amdgcn_mfma_f32_16x16x32_bf16(af[m], bf[n], acc[m][n], 0, 0, 0);
    }
    __syncthreads();
  }
#pragma unroll
  for (int m = 0; m < 4; ++m) {
#pragma unroll
    for (int n = 0; n < 4; ++n) {
      const int gr0 = brow + wr + m * 16 + lg * 4;
      const int gc = bcol + wc + n * 16 + lr;
      if (OUTMODE == 2) {
        ushort4v o;
#pragma unroll
        for (int r = 0; r < 4; ++r) o[r] = f2bf((acc[m][n][r] + bias[gc]) * oscale);
        const int bb = gr0 >> 11, ss = gr0 & 2047, hh = gc >> 6, dd = gc & 63;
        *reinterpret_cast<ushort4v*>(obf + ((size_t)(bb * NH_ + hh) * HD_ + dd) * S_ + ss) = o;
      } else {
#pragma unroll
        for (int r = 0; r < 4; ++r) {
          const int gr = gr0 + r;
          const float val = (acc[m][n][r] + bias[gc]) * oscale;
          if (OUTMODE == 0) {
            const int bb = gr >> 11, ss = gr & 2047, hh = gc >> 6, dd = gc & 63;
            obf[(((size_t)(bb * NH_ + hh)) * S_ + ss) * HD_ + dd] = f2bf(val);
          } else {
            of32[(size_t)gr * H_ + gc] = val;
          }
        }
      }
    }
  }
}

// Q is pre-scaled by 0.125*log2(e) so attention can exp2() the raw MFMA output.
#define QSCL 0.1803368801111244f

__global__ __launch_bounds__(256, 4) void gemm_qkv(
    const unsigned short* __restrict__ xq, const unsigned short* __restrict__ xk,
    const unsigned short* __restrict__ wt,
    const float* __restrict__ bq, const float* __restrict__ bk,
    unsigned short* __restrict__ qh, unsigned short* __restrict__ kh) {
  const int z = blockIdx.z;
  const unsigned short* X = z == 0 ? xq : xk;
  const unsigned short* W = wt + (size_t)z * H_ * H_;
  const float* bias = z == 0 ? bq : bk;
  unsigned short* out = z == 0 ? qh : kh;
  const float scl = z == 0 ? QSCL : 1.0f;
  gemm_body<0>(X, W, bias, scl, out, nullptr);
}

__global__ __launch_bounds__(256, 4) void gemm_v(
    const unsigned short* __restrict__ xv, const unsigned short* __restrict__ wt,
    const float* __restrict__ bv, unsigned short* __restrict__ vtv) {
  gemm_body<2>(xv, wt + (size_t)2 * H_ * H_, bv, 1.0f, vtv, nullptr);
}

__global__ __launch_bounds__(256, 4) void gemm_out(
    const unsigned short* __restrict__ ao, const unsigned short* __restrict__ wt,
    const float* __restrict__ bo, float* __restrict__ out) {
  gemm_body<1>(ao, wt, bo, 1.0f, nullptr, out);
}

// ---------------- flash attention: 32x32 swapped-QK, in-register softmax ----------
// 2048 blocks x 128 threads (2 waves x 32 q-rows = 64 q-rows/block); same
// 4-heads/XCD residency map as r10 (FETCH 28.8 MB verified). LDS padded to
// ~35 KB -> 4 blocks/CU. Swapped QK^T (A=K, B=Q^T) puts each q-row's scores
// in-lane; P -> PV A-fragments via cvt_pk + permlane32_swap (no LDS roundtrip).
#if defined(__has_builtin)
#if __has_builtin(__builtin_amdgcn_permlane32_swap)
#define HAVE_PLSWAP 1
#endif
#endif

__global__ __launch_bounds__(128, 2) void attn_kernel(
    const unsigned short* __restrict__ qh, const unsigned short* __restrict__ kh,
    const unsigned short* __restrict__ vt, const unsigned long long* __restrict__ mb,
    unsigned short* __restrict__ ao) {
  constexpr int KSZ = 64 * 64 + 256;  // pad: 2*(K+V) = ~34.8 KB -> exactly 4 blocks/CU
  __shared__ unsigned short Ks[2][KSZ];
  __shared__ unsigned short Vs[2][KSZ];
  const int t = threadIdx.x, l = t & 63, w = t >> 6;
  const int lq = l & 31;   // q-column (C/D col) / A-row index
  const int lg = l >> 5;   // k-group (0/1)
  const int flat = blockIdx.x;
  const int xcd = flat & 7;
  const int gen = flat >> 10;
  const int hh = (flat >> 8) & 3;
  const int qt = (flat >> 3) & 31;
  const int bh = gen * 32 + xcd * 4 + hh;
  const int b = bh >> 4, h = bh & 15;
  const unsigned short* qptr = qh + (size_t)bh * S_ * HD_;
  const unsigned short* kptr = kh + (size_t)bh * S_ * HD_;
  const unsigned short* vptr = vt + (size_t)bh * HD_ * S_;
  const unsigned long long* mbase = mb + (size_t)b * S_ * (S_ / 64);
  const int qbase = qt * 64 + w * 32;

  // Q^T B-fragments: lane holds Q[qbase+lq][ks*16 + lg*8 + e]
  short8 qreg[4];
  {
    const unsigned short* qp = qptr + (size_t)(qbase + lq) * HD_ + lg * 8;
#pragma unroll
    for (int ks = 0; ks < 4; ++ks)
      qreg[ks] = *reinterpret_cast<const short8*>(qp + ks * 16);
  }
  short8 ones;
#pragma unroll
  for (int jj = 0; jj < 8; ++jj) ones[jj] = (short)0x3F80;

  // staging: 512 chunks of 16B per tile (K and V each), 4 chunks/thread each
  int srow[4], skl[4];
#pragma unroll
  for (int j = 0; j < 4; ++j) {
    const int c = t + j * 128;
    srow[j] = c >> 3;
    skl[j] = ((c & 7) ^ ((c >> 3) & 7)) * 8;
  }
  const size_t moff = (size_t)(qbase + lq) * (S_ / 64);

  // prologue: stage tile 0 into buffer 0
#pragma unroll
  for (int j = 0; j < 4; ++j) {
    ALDS16(kptr + (size_t)srow[j] * HD_ + skl[j], Ks[0] + (t + j * 128) * 8);
    ALDS16(vptr + (size_t)srow[j] * S_ + skl[j], Vs[0] + (t + j * 128) * 8);
  }
  __syncthreads();

  f32x16 acc_o0 = {}, acc_o1 = {}, acc_l = {};
  int cur = 0;

  for (int kv = 0; kv < S_; kv += 64) {
    const unsigned long long mwv = mbase[moff + (kv >> 6)];

    // stage NEXT tile into other buffer
    const int nkv = (kv + 64 < S_) ? kv + 64 : 0;
#pragma unroll
    for (int j = 0; j < 4; ++j) {
      ALDS16(kptr + (size_t)(nkv + srow[j]) * HD_ + skl[j], Ks[cur ^ 1] + (t + j * 128) * 8);
      ALDS16(vptr + (size_t)srow[j] * S_ + nkv + skl[j], Vs[cur ^ 1] + (t + j * 128) * 8);
    }

    const unsigned short* Kc = Ks[cur];
    const unsigned short* Vc = Vs[cur];

    // S^T = K·Q^T  (two 32-kv sub-tiles)
    f32x16 s0 = {}, s1 = {};
#pragma unroll
    for (int ks = 0; ks < 4; ++ks) {
      const short8 kf0 = *reinterpret_cast<const short8*>(
          Kc + lq * 64 + (((ks * 2 + lg) ^ (lq & 7)) * 8));
      s0 = __builtin_amdgcn_mfma_f32_32x32x16_bf16(kf0, qreg[ks], s0, 0, 0, 0);
    }
#pragma unroll
    for (int ks = 0; ks < 4; ++ks) {
      const short8 kf1 = *reinterpret_cast<const short8*>(
          Kc + (32 + lq) * 64 + (((ks * 2 + lg) ^ (lq & 7)) * 8));
      s1 = __builtin_amdgcn_mfma_f32_32x32x16_bf16(kf1, qreg[ks], s1, 0, 0, 0);
    }

    // exp2 + mask (in-register; one u64 mask word per lane)
    const unsigned sh0 = (unsigned)(mwv >> (lg * 4));
    const unsigned sh1 = (unsigned)(mwv >> (32 + lg * 4));
    float p0[16], p1[16];
#pragma unroll
    for (int r = 0; r < 16; ++r) {
      const int pos = (r & 3) + 8 * (r >> 2);
      union { float f; unsigned u; } c0, c1;
      c0.f = __builtin_amdgcn_exp2f(s0[r]);
      c0.u &= (0u - ((sh0 >> pos) & 1u));
      p0[r] = c0.f;
      c1.f = __builtin_amdgcn_exp2f(s1[r]);
      c1.u &= (0u - ((sh1 >> pos) & 1u));
      p1[r] = c1.f;
    }

    // P -> A-fragments via cvt_pk + permlane32_swap
    short8 pfrag[4];
#pragma unroll
    for (int ks2 = 0; ks2 < 4; ++ks2) {
      const float* pt = (ks2 >> 1) ? p1 : p0;
      const int base = (ks2 & 1) * 8;
      const unsigned pkA = cvtpk_bf16(pt[base + 0], pt[base + 1]);
      const unsigned pkB = cvtpk_bf16(pt[base + 2], pt[base + 3]);
      const unsigned pkC = cvtpk_bf16(pt[base + 4], pt[base + 5]);
      const unsigned pkD = cvtpk_bf16(pt[base + 6], pt[base + 7]);
      union { unsigned u[4]; short8 s; } fr;
#ifdef HAVE_PLSWAP
      const uint2v r02 = __builtin_amdgcn_permlane32_swap(pkA, pkC, false, false);
      const uint2v r13 = __builtin_amdgcn_permlane32_swap(pkB, pkD, false, false);
      fr.u[0] = r02[0]; fr.u[1] = r13[0]; fr.u[2] = r02[1]; fr.u[3] = r13[1];
#else
      const unsigned pA_sw = (unsigned)__shfl_xor((int)pkA, 32);
      const unsigned pB_sw = (unsigned)__shfl_xor((int)pkB, 32);
      const unsigned pC_sw = (unsigned)__shfl_xor((int)pkC, 32);
      const unsigned pD_sw = (unsigned)__shfl_xor((int)pkD, 32);
      fr.u[0] = lg ? pC_sw : pkA;
      fr.u[1] = lg ? pD_sw : pkB;
      fr.u[2] = lg ? pkC : pA_sw;
      fr.u[3] = lg ? pkD : pB_sw;
#endif
      pfrag[ks2] = fr.s;
    }

    // l-sum (MFMA-ones) + PV
    __builtin_amdgcn_s_setprio(1);
#pragma unroll
    for (int ks2 = 0; ks2 < 4; ++ks2)
      acc_l = __builtin_amdgcn_mfma_f32_32x32x16_bf16(pfrag[ks2], ones, acc_l, 0, 0, 0);
#pragma unroll
    for (int ks2 = 0; ks2 < 4; ++ks2) {
      const short8 vf0 = *reinterpret_cast<const short8*>(
          Vc + lq * 64 + (((ks2 * 2 + lg) ^ (lq & 7)) * 8));
      acc_o0 = __builtin_amdgcn_mfma_f32_32x32x16_bf16(pfrag[ks2], vf0, acc_o0, 0, 0, 0);
      const short8 vf1 = *reinterpret_cast<const short8*>(
          Vc + (32 + lq) * 64 + (((ks2 * 2 + lg) ^ (lq & 7)) * 8));
      acc_o1 = __builtin_amdgcn_mfma_f32_32x32x16_bf16(pfrag[ks2], vf1, acc_o1, 0, 0, 0);
    }
    __builtin_amdgcn_s_setprio(0);
    __syncthreads();
    cur ^= 1;
  }

  // epilogue: divide by row-sum, store
#pragma unroll
  for (int r = 0; r < 16; ++r) {
    const int qrow = qbase + (r & 3) + 8 * (r >> 2) + 4 * lg;
    const float inv = __builtin_amdgcn_rcpf(acc_l[r]);
    unsigned short* orow = ao + ((size_t)b * S_ + qrow) * H_ + h * HD_ + lq;
    orow[0] = f2bf(acc_o0[r] * inv);
    orow[32] = f2bf(acc_o1[r] * inv);
  }
}

extern "C" void kernel_launch(void* const* d_in, const int* in_sizes, int n_in,
                              void* d_out, int out_size, void* d_ws, size_t ws_size,
                              hipStream_t stream) {
  (void)in_sizes; (void)n_in; (void)out_size; (void)ws_size;
  const float* query = (const float*)d_in[0];
  const float* key_  = (const float*)d_in[1];
  const float* value = (const float*)d_in[2];
  const float* mask  = (const float*)d_in[3];
  const float* Wq = (const float*)d_in[4];
  const float* bq = (const float*)d_in[5];
  const float* Wk = (const float*)d_in[6];
  const float* bk = (const float*)d_in[7];
  const float* Wv = (const float*)d_in[8];
  const float* bv = (const float*)d_in[9];
  const float* Wo = (const float*)d_in[10];
  const float* bo = (const float*)d_in[11];
  float* out = (float*)d_out;

  char* ws = (char*)d_ws;
  const size_t MB16 = (size_t)1 << 24;
  unsigned short* XQ = (unsigned short*)(ws + 0 * MB16);
  unsigned short* XK = (unsigned short*)(ws + 1 * MB16);
  unsigned short* XV = (unsigned short*)(ws + 2 * MB16);
  unsigned short* QH = (unsigned short*)(ws + 3 * MB16);
  unsigned short* KH = (unsigned short*)(ws + 4 * MB16);
  unsigned short* VT = (unsigned short*)(ws + 5 * MB16);  // V written transposed
  unsigned short* WT = (unsigned short*)(ws + 6 * MB16);  // 8 MB
  unsigned long long* MBits = (unsigned long long*)(ws + 6 * MB16 + (size_t)4 * H_ * H_ * 2);  // 2 MB
  unsigned short* AO = XQ;  // reuse: XQ dead after gemm_qkv

  cvt_in<<<dim3(4096, 1, 3), 256, 0, stream>>>(query, key_, value, XQ, XK, XV);
  packmask<<<dim3(2048), 256, 0, stream>>>(mask, MBits);
  cvt_w<<<dim3(16, 16, 4), 256, 0, stream>>>(Wq, Wk, Wv, Wo, WT);
  gemm_qkv<<<dim3(64, 8, 2), 256, 0, stream>>>(XQ, XK, WT, bq, bk, QH, KH);
  gemm_v<<<dim3(64, 8), 256, 0, stream>>>(XV, WT, bv, VT);
  attn_kernel<<<dim3(2048), 128, 0, stream>>>(QH, KH, VT, MBits, AO);
  gemm_out<<<dim3(64, 8), 256, 0, stream>>>(AO, WT + 3 * (size_t)H_ * H_, bo, out);
}

// Round 15
// 257.051 us; speedup vs baseline: 1.0645x; 1.0645x over previous
//
#include <hip/hip_runtime.h>
#include <hip/hip_bf16.h>
#include <stdint.h>

#define B_ 4
#define S_ 2048
#define H_ 1024
#define NH_ 16
#define HD_ 64

typedef __attribute__((ext_vector_type(8))) short short8;
typedef __attribute__((ext_vector_type(4))) float f32x4;
typedef __attribute__((ext_vector_type(4))) unsigned short ushort4v;

__device__ __forceinline__ unsigned short f2bf(float f) {
  union { float f; unsigned u; } x; x.f = f;
  unsigned r = x.u + 0x7fffu + ((x.u >> 16) & 1u);
  return (unsigned short)(r >> 16);
}

#define ALDS16(g, l) \
  __builtin_amdgcn_global_load_lds((const __attribute__((address_space(1))) void*)(g), \
                                   (__attribute__((address_space(3))) void*)(l), 16, 0, 0)

// ---------------- input fp32 -> bf16 convert ----------------
__global__ __launch_bounds__(256) void cvt_in(
    const float* __restrict__ q, const float* __restrict__ k, const float* __restrict__ v,
    unsigned short* __restrict__ oq, unsigned short* __restrict__ ok2, unsigned short* __restrict__ ov) {
  const int z = blockIdx.z;
  const float* src = z == 0 ? q : (z == 1 ? k : v);
  unsigned short* dst = z == 0 ? oq : (z == 1 ? ok2 : ov);
  const size_t i = ((size_t)blockIdx.x * 256 + threadIdx.x) * 8;
  const f32x4 a = *reinterpret_cast<const f32x4*>(src + i);
  const f32x4 c = *reinterpret_cast<const f32x4*>(src + i + 4);
  short8 o;
#pragma unroll
  for (int j = 0; j < 4; ++j) { o[j] = (short)f2bf(a[j]); o[j + 4] = (short)f2bf(c[j]); }
  *reinterpret_cast<short8*>(dst + i) = o;
}

// ---------------- mask fp32 -> bit pack (bit set = KEEP, i.e. mask==0) ----------------
__global__ __launch_bounds__(256) void packmask(
    const float* __restrict__ mask, unsigned long long* __restrict__ mb) {
  const int w = threadIdx.x >> 6, lane = threadIdx.x & 63;
  const int wbase = (blockIdx.x * 4 + w) * 32;
#pragma unroll 8
  for (int i = 0; i < 32; ++i) {
    const float v = mask[(size_t)(wbase + i) * 64 + lane];
    const unsigned long long bits = __ballot(v == 0.0f);
    if (lane == 0) mb[wbase + i] = bits;
  }
}

// ---------------- weight fp32 -> bf16 transpose (Wt[n][k] = W[k][n]) ----------------
__global__ __launch_bounds__(256) void cvt_w(
    const float* __restrict__ Wq, const float* __restrict__ Wk,
    const float* __restrict__ Wv, const float* __restrict__ Wo,
    unsigned short* __restrict__ wt) {
  __shared__ float tile[64][65];
  const int z = blockIdx.z;
  const float* W = z == 0 ? Wq : (z == 1 ? Wk : (z == 2 ? Wv : Wo));
  unsigned short* out = wt + (size_t)z * H_ * H_;
  const int t = threadIdx.x;
  const int r0 = blockIdx.y * 64, c0 = blockIdx.x * 64;
  const int tr = t >> 4, tc = (t & 15) * 4;
#pragma unroll
  for (int rr = 0; rr < 4; ++rr) {
    const int row = rr * 16 + tr;
    const f32x4 val = *reinterpret_cast<const f32x4*>(W + (size_t)(r0 + row) * H_ + c0 + tc);
#pragma unroll
    for (int j = 0; j < 4; ++j) tile[row][tc + j] = val[j];
  }
  __syncthreads();
#pragma unroll
  for (int rr = 0; rr < 4; ++rr) {
    const int c = rr * 16 + tr;
    ushort4v o;
#pragma unroll
    for (int j = 0; j < 4; ++j) o[j] = f2bf(tile[tc + j][c]);
    *reinterpret_cast<ushort4v*>(out + (size_t)(c0 + c) * H_ + r0 + tc) = o;
  }
}

// ---------------- GEMM body: C = (X @ Wt^T + bias) * oscale ----------------
// OUTMODE 0: bf16 head-split [B,NH,S,HD]. 1: fp32 flat [M,H]. 2: bf16 V-transposed.
template <int OUTMODE>
__device__ __forceinline__ void gemm_body(
    const unsigned short* __restrict__ X, const unsigned short* __restrict__ Wt,
    const float* __restrict__ bias, float oscale, unsigned short* __restrict__ obf,
    float* __restrict__ of32) {
  __shared__ unsigned short As[128 * 64];
  __shared__ unsigned short Bs[128 * 64];
  const int t = threadIdx.x;
  const int w = t >> 6, l = t & 63;
  const int lr = l & 15, lg = l >> 4;
  const int brow = blockIdx.x * 128, bcol = blockIdx.y * 128;
  const int wr = (w >> 1) * 64, wc = (w & 1) * 64;
  f32x4 acc[4][4] = {};
  const unsigned short* xb = X + (size_t)brow * 1024;
  const unsigned short* wb = Wt + (size_t)bcol * 1024;
  int srow[4], skl[4];
#pragma unroll
  for (int j = 0; j < 4; ++j) {
    const int c = t + j * 256;
    srow[j] = c >> 3;
    skl[j] = ((c & 7) ^ ((c >> 3) & 7)) * 8;
  }
  for (int kt = 0; kt < 1024; kt += 64) {
#pragma unroll
    for (int j = 0; j < 4; ++j) {
      ALDS16(xb + (size_t)srow[j] * 1024 + kt + skl[j], As + (t + j * 256) * 8);
      ALDS16(wb + (size_t)srow[j] * 1024 + kt + skl[j], Bs + (t + j * 256) * 8);
    }
    __syncthreads();
#pragma unroll
    for (int kk = 0; kk < 2; ++kk) {
      short8 af[4], bf[4];
#pragma unroll
      for (int m = 0; m < 4; ++m) {
        const int ra = wr + m * 16 + lr;
        af[m] = *reinterpret_cast<const short8*>(As + ra * 64 + ((kk * 4 + lg) ^ (ra & 7)) * 8);
      }
#pragma unroll
      for (int n = 0; n < 4; ++n) {
        const int rb = wc + n * 16 + lr;
        bf[n] = *reinterpret_cast<const short8*>(Bs + rb * 64 + ((kk * 4 + lg) ^ (rb & 7)) * 8);
      }
#pragma unroll
      for (int m = 0; m < 4; ++m)
#pragma unroll
        for (int n = 0; n < 4; ++n)
          acc[m][n] = __builtin_amdgcn_mfma_f32_16x16x32_bf16(af[m], bf[n], acc[m][n], 0, 0, 0);
    }
    __syncthreads();
  }
#pragma unroll
  for (int m = 0; m < 4; ++m) {
#pragma unroll
    for (int n = 0; n < 4; ++n) {
      const int gr0 = brow + wr + m * 16 + lg * 4;
      const int gc = bcol + wc + n * 16 + lr;
      if (OUTMODE == 2) {
        ushort4v o;
#pragma unroll
        for (int r = 0; r < 4; ++r) o[r] = f2bf((acc[m][n][r] + bias[gc]) * oscale);
        const int bb = gr0 >> 11, ss = gr0 & 2047, hh = gc >> 6, dd = gc & 63;
        *reinterpret_cast<ushort4v*>(obf + ((size_t)(bb * NH_ + hh) * HD_ + dd) * S_ + ss) = o;
      } else {
#pragma unroll
        for (int r = 0; r < 4; ++r) {
          const int gr = gr0 + r;
          const float val = (acc[m][n][r] + bias[gc]) * oscale;
          if (OUTMODE == 0) {
            const int bb = gr >> 11, ss = gr & 2047, hh = gc >> 6, dd = gc & 63;
            obf[(((size_t)(bb * NH_ + hh)) * S_ + ss) * HD_ + dd] = f2bf(val);
          } else {
            of32[(size_t)gr * H_ + gc] = val;
          }
        }
      }
    }
  }
}

// Q is pre-scaled by 0.125*log2(e) so attention can exp2() the raw MFMA output.
#define QSCL 0.1803368801111244f

__global__ __launch_bounds__(256, 4) void gemm_qkv(
    const unsigned short* __restrict__ xq, const unsigned short* __restrict__ xk,
    const unsigned short* __restrict__ wt,
    const float* __restrict__ bq, const float* __restrict__ bk,
    unsigned short* __restrict__ qh, unsigned short* __restrict__ kh) {
  const int z = blockIdx.z;
  const unsigned short* X = z == 0 ? xq : xk;
  const unsigned short* W = wt + (size_t)z * H_ * H_;
  const float* bias = z == 0 ? bq : bk;
  unsigned short* out = z == 0 ? qh : kh;
  const float scl = z == 0 ? QSCL : 1.0f;
  gemm_body<0>(X, W, bias, scl, out, nullptr);
}

__global__ __launch_bounds__(256, 4) void gemm_v(
    const unsigned short* __restrict__ xv, const unsigned short* __restrict__ wt,
    const float* __restrict__ bv, unsigned short* __restrict__ vtv) {
  gemm_body<2>(xv, wt + (size_t)2 * H_ * H_, bv, 1.0f, vtv, nullptr);
}

__global__ __launch_bounds__(256, 4) void gemm_out(
    const unsigned short* __restrict__ ao, const unsigned short* __restrict__ wt,
    const float* __restrict__ bo, float* __restrict__ out) {
  gemm_body<1>(ao, wt, bo, 1.0f, nullptr, out);
}

// ---------------- flash attention (r10/r12 structure, best-known) ----------------
// 2048 blocks x 4 waves x 16 q-rows, 40 KB LDS, 4 blocks/CU; 4-heads/XCD
// residency (FETCH 28.8 MB verified r7-r13). 16x16 fragment geometry is
// bank-conflict-free (0 measured); 32x32 variant is structurally 4-way
// conflicted under global_load_lds's linear-dest constraint (r14: 8.4M).
__global__ __launch_bounds__(256, 4) void attn_kernel(
    const unsigned short* __restrict__ qh, const unsigned short* __restrict__ kh,
    const unsigned short* __restrict__ vt, const unsigned long long* __restrict__ mb,
    unsigned short* __restrict__ ao) {
  __shared__ unsigned short Ks[2][64 * 64];
  __shared__ unsigned short Vs[2][64 * 64];
  __shared__ unsigned short Ps[4][16 * 64];
  const int t = threadIdx.x, w = t >> 6, l = t & 63;
  const int lr = l & 15, lg = l >> 4;
  const int flat = blockIdx.x;
  const int xcd = flat & 7;
  const int gen = flat >> 10;
  const int hh = (flat >> 8) & 3;
  const int qt = (flat >> 3) & 31;
  const int bh = gen * 32 + xcd * 4 + hh;
  const int b = bh >> 4, h = bh & 15;
  const unsigned short* qptr = qh + (size_t)bh * S_ * HD_;
  const unsigned short* kptr = kh + (size_t)bh * S_ * HD_;
  const unsigned short* vptr = vt + (size_t)bh * HD_ * S_;
  const unsigned long long* mbase = mb + (size_t)b * S_ * (S_ / 64);
  const int qbase = qt * 64 + w * 16;

  short8 qf[2];
  {
    const unsigned short* qp = qptr + (size_t)(qbase + lr) * HD_ + lg * 8;
    qf[0] = *reinterpret_cast<const short8*>(qp);
    qf[1] = *reinterpret_cast<const short8*>(qp + 32);
  }
  short8 ones;
#pragma unroll
  for (int jj = 0; jj < 8; ++jj) ones[jj] = (short)0x3F80;

  const int si0 = t, si1 = t + 256;
  const int srow0 = si0 >> 3, sk0 = ((si0 & 7) ^ (srow0 & 7)) * 8;
  const int srow1 = si1 >> 3, sk1 = ((si1 & 7) ^ (srow1 & 7)) * 8;
  const unsigned short* ksrc0 = kptr + (size_t)srow0 * HD_ + sk0;
  const unsigned short* ksrc1 = kptr + (size_t)srow1 * HD_ + sk1;
  const unsigned short* vsrc0 = vptr + (size_t)srow0 * S_ + sk0;
  const unsigned short* vsrc1 = vptr + (size_t)srow1 * S_ + sk1;
  size_t moff[4];
#pragma unroll
  for (int r = 0; r < 4; ++r)
    moff[r] = (size_t)(qbase + lg * 4 + r) * (S_ / 64);

  const int fragoff0 = lr * 64 + ((0 + lg) ^ (lr & 7)) * 8;
  const int fragoff1 = lr * 64 + ((4 + lg) ^ (lr & 7)) * 8;
  int pwoff[4][4];
#pragma unroll
  for (int r = 0; r < 4; ++r) {
    const int row = lg * 4 + r;
#pragma unroll
    for (int n = 0; n < 4; ++n) {
      const int col = n * 16 + lr;
      pwoff[r][n] = row * 64 + ((col >> 3) ^ (row & 7)) * 8 + (col & 7);
    }
  }

  ALDS16(ksrc0, Ks[0] + si0 * 8);
  ALDS16(ksrc1, Ks[0] + si1 * 8);
  ALDS16(vsrc0, Vs[0] + si0 * 8);
  ALDS16(vsrc1, Vs[0] + si1 * 8);
  __syncthreads();

  f32x4 acc_o[4] = {};
  f32x4 acc_l = {};
  unsigned short* pw = Ps[w];
  int cur = 0;

  for (int kv = 0; kv < S_; kv += 64) {
    unsigned msel[4][4];
#pragma unroll
    for (int r = 0; r < 4; ++r) {
      const unsigned long long mwv = mbase[moff[r] + (kv >> 6)];
      const unsigned long long sh = mwv >> lr;
      const unsigned lo = (unsigned)sh, hi = (unsigned)(sh >> 32);
      msel[r][0] = 0u - (lo & 1u);
      msel[r][1] = 0u - ((lo >> 16) & 1u);
      msel[r][2] = 0u - (hi & 1u);
      msel[r][3] = 0u - ((hi >> 16) & 1u);
    }

    const int nkv = (kv + 64 < S_) ? kv + 64 : 0;
    ALDS16(ksrc0 + (size_t)nkv * HD_, Ks[cur ^ 1] + si0 * 8);
    ALDS16(ksrc1 + (size_t)nkv * HD_, Ks[cur ^ 1] + si1 * 8);
    ALDS16(vsrc0 + nkv, Vs[cur ^ 1] + si0 * 8);
    ALDS16(vsrc1 + nkv, Vs[cur ^ 1] + si1 * 8);

    const unsigned short* Kf0 = Ks[cur] + fragoff0;
    const unsigned short* Kf1 = Ks[cur] + fragoff1;
    const unsigned short* Vf0 = Vs[cur] + fragoff0;
    const unsigned short* Vf1 = Vs[cur] + fragoff1;

    float p[4][4];
#pragma unroll
    for (int n = 0; n < 4; ++n) {
      const short8 kf0 = *reinterpret_cast<const short8*>(Kf0 + n * 1024);
      const short8 kf1 = *reinterpret_cast<const short8*>(Kf1 + n * 1024);
      f32x4 sc = {};
      sc = __builtin_amdgcn_mfma_f32_16x16x32_bf16(qf[0], kf0, sc, 0, 0, 0);
      sc = __builtin_amdgcn_mfma_f32_16x16x32_bf16(qf[1], kf1, sc, 0, 0, 0);
#pragma unroll
      for (int r = 0; r < 4; ++r) {
        union { float f; unsigned u; } cv;
        cv.f = __builtin_amdgcn_exp2f(sc[r]);
        cv.u &= msel[r][n];
        p[n][r] = cv.f;
      }
    }

#pragma unroll
    for (int r = 0; r < 4; ++r)
#pragma unroll
      for (int n = 0; n < 4; ++n) {
        union { float f; unsigned u; } cv; cv.f = p[n][r];
        pw[pwoff[r][n]] = (unsigned short)(cv.u >> 16);
      }
    short8 pf0 = *reinterpret_cast<const short8*>(pw + fragoff0);
    short8 pf1 = *reinterpret_cast<const short8*>(pw + fragoff1);
    acc_l = __builtin_amdgcn_mfma_f32_16x16x32_bf16(pf0, ones, acc_l, 0, 0, 0);
    acc_l = __builtin_amdgcn_mfma_f32_16x16x32_bf16(pf1, ones, acc_l, 0, 0, 0);

    __builtin_amdgcn_s_setprio(1);
#pragma unroll
    for (int d = 0; d < 4; ++d) {
      const short8 vf0 = *reinterpret_cast<const short8*>(Vf0 + d * 1024);
      const short8 vf1 = *reinterpret_cast<const short8*>(Vf1 + d * 1024);
      acc_o[d] = __builtin_amdgcn_mfma_f32_16x16x32_bf16(pf0, vf0, acc_o[d], 0, 0, 0);
      acc_o[d] = __builtin_amdgcn_mfma_f32_16x16x32_bf16(pf1, vf1, acc_o[d], 0, 0, 0);
    }
    __builtin_amdgcn_s_setprio(0);
    __syncthreads();
    cur ^= 1;
  }

#pragma unroll
  for (int r = 0; r < 4; ++r) {
    const float inv = __builtin_amdgcn_rcpf(acc_l[r]);
    const int qrow = qbase + lg * 4 + r;
    unsigned short* orow = ao + ((size_t)b * S_ + qrow) * H_ + h * HD_;
#pragma unroll
    for (int d = 0; d < 4; ++d)
      orow[d * 16 + lr] = f2bf(acc_o[d][r] * inv);
  }
}

extern "C" void kernel_launch(void* const* d_in, const int* in_sizes, int n_in,
                              void* d_out, int out_size, void* d_ws, size_t ws_size,
                              hipStream_t stream) {
  (void)in_sizes; (void)n_in; (void)out_size; (void)ws_size;
  const float* query = (const float*)d_in[0];
  const float* key_  = (const float*)d_in[1];
  const float* value = (const float*)d_in[2];
  const float* mask  = (const float*)d_in[3];
  const float* Wq = (const float*)d_in[4];
  const float* bq = (const float*)d_in[5];
  const float* Wk = (const float*)d_in[6];
  const float* bk = (const float*)d_in[7];
  const float* Wv = (const float*)d_in[8];
  const float* bv = (const float*)d_in[9];
  const float* Wo = (const float*)d_in[10];
  const float* bo = (const float*)d_in[11];
  float* out = (float*)d_out;

  char* ws = (char*)d_ws;
  const size_t MB16 = (size_t)1 << 24;
  unsigned short* XQ = (unsigned short*)(ws + 0 * MB16);
  unsigned short* XK = (unsigned short*)(ws + 1 * MB16);
  unsigned short* XV = (unsigned short*)(ws + 2 * MB16);
  unsigned short* QH = (unsigned short*)(ws + 3 * MB16);
  unsigned short* KH = (unsigned short*)(ws + 4 * MB16);
  unsigned short* VT = (unsigned short*)(ws + 5 * MB16);  // V written transposed
  unsigned short* WT = (unsigned short*)(ws + 6 * MB16);  // 8 MB
  unsigned long long* MBits = (unsigned long long*)(ws + 6 * MB16 + (size_t)4 * H_ * H_ * 2);  // 2 MB
  unsigned short* AO = XQ;  // reuse: XQ dead after gemm_qkv

  cvt_in<<<dim3(4096, 1, 3), 256, 0, stream>>>(query, key_, value, XQ, XK, XV);
  packmask<<<dim3(2048), 256, 0, stream>>>(mask, MBits);
  cvt_w<<<dim3(16, 16, 4), 256, 0, stream>>>(Wq, Wk, Wv, Wo, WT);
  gemm_qkv<<<dim3(64, 8, 2), 256, 0, stream>>>(XQ, XK, WT, bq, bk, QH, KH);
  gemm_v<<<dim3(64, 8), 256, 0, stream>>>(XV, WT, bv, VT);
  attn_kernel<<<dim3(2048), 256, 0, stream>>>(QH, KH, VT, MBits, AO);
  gemm_out<<<dim3(64, 8), 256, 0, stream>>>(AO, WT + 3 * (size_t)H_ * H_, bo, out);
}